// Round 7
// baseline (243.343 us; speedup 1.0000x reference)
//
#include <hip/hip_runtime.h>
#include <hip/hip_bf16.h>

#define SEP_ID 2
#define S_LEN  4096
#define HID    768
#define MAXS   64

using short8  = __attribute__((ext_vector_type(8))) short;  // 8 bf16 (4 VGPRs)
using floatx4 = __attribute__((ext_vector_type(4))) float;  // MFMA accumulator

__device__ __forceinline__ float gelu_exact(float x) {
    return 0.5f * x * (1.0f + erff(x * 0.70710678118654752f));
}

__device__ __forceinline__ unsigned pack_bf16x2(float lo, float hi) {
    __hip_bfloat16 a = __float2bfloat16(lo);
    __hip_bfloat16 b = __float2bfloat16(hi);
    return ((unsigned)*(unsigned short*)&b << 16) | (unsigned)*(unsigned short*)&a;
}

// ---------------------------------------------------------------------------
// K1 "stage1": pool blocks [0,512) + zero blocks [512,528) for x2/cnt.
// Pool blocks self-compute bounds from ids (shfl prefix-scan), then mean-pool
// with float4 columns and an 8-row unroll. No weight transpose any more.
// ---------------------------------------------------------------------------
__global__ __launch_bounds__(256) void stage1_kernel(const int* __restrict__ ids,
                                                     const float* __restrict__ hidden,
                                                     __hip_bfloat16* __restrict__ sentb,
                                                     float* __restrict__ x2,
                                                     int* __restrict__ cnt) {
    __shared__ __align__(16) int smem[4100];
    const int blk = blockIdx.x;
    const int t = threadIdx.x;

    if (blk >= 512) {
        // zero x2 (512x256 f32 = 512 KB over 16 blocks) and cnt
        float4* p = (float4*)x2 + (size_t)(blk - 512) * 2048 + t;
        float4 z = {0.f, 0.f, 0.f, 0.f};
        #pragma unroll
        for (int i = 0; i < 8; ++i) p[i * 256] = z;
        if (blk == 512 && t < 16) cnt[t] = 0;
        return;
    }

    // ---- self-bounds ----
    int* sep_pos = smem;                  // 4096 ints
    int* wtot    = sep_pos + 4096;        // 4 ints
    const int sidx = blk;
    const int b = sidx >> 6, m = sidx & 63;
    const int* row = ids + (size_t)b * S_LEN;
    const int lane = t & 63, w = t >> 6;

    int local[16]; int c = 0;
    const int base = t * 16;
    #pragma unroll
    for (int q = 0; q < 4; ++q) {
        int4 v = ((const int4*)row)[t * 4 + q];
        if (v.x == SEP_ID) local[c++] = base + q * 4 + 0;
        if (v.y == SEP_ID) local[c++] = base + q * 4 + 1;
        if (v.z == SEP_ID) local[c++] = base + q * 4 + 2;
        if (v.w == SEP_ID) local[c++] = base + q * 4 + 3;
    }
    int scan = c;                              // inclusive wave prefix
    #pragma unroll
    for (int off = 1; off < 64; off <<= 1) {
        int n = __shfl_up(scan, off);
        if (lane >= off) scan += n;
    }
    if (lane == 63) wtot[w] = scan;
    __syncthreads();
    int wbase = 0;
    for (int i = 0; i < w; ++i) wbase += wtot[i];
    const int o = wbase + scan - c;
    for (int i = 0; i < c; ++i) sep_pos[o + i] = local[i];
    __syncthreads();
    const int n_sep = wtot[0] + wtot[1] + wtot[2] + wtot[3];

    // ---- reference segment semantics ----
    int start = 0, cntok = 0;
    if (n_sep == 0) {
        if (m == 0) { start = 0; cntok = S_LEN; }
    } else if (m < n_sep) {
        if (m == 0) { start = 0; cntok = sep_pos[0] + 1; }   // includes first sep
        else { start = sep_pos[m - 1] + 1; cntok = sep_pos[m] - sep_pos[m - 1] - 1; }
    } else if (m == n_sep) {
        start = sep_pos[n_sep - 1] + 1;                      // trailing segment
        cntok = (S_LEN - 1) - start;                         // excludes token S-1
        if (cntok < 0) cntok = 0;
    }

    // ---- mean pool ----
    if (t < 192) {
        const float4* bp = (const float4*)(hidden + ((size_t)b * S_LEN + start) * HID);
        float ax = 0.f, ay = 0.f, az = 0.f, aw = 0.f;
        int i = 0;
        for (; i + 8 <= cntok; i += 8) {
            float4 v[8];
            #pragma unroll
            for (int j = 0; j < 8; ++j) v[j] = bp[(size_t)(i + j) * 192 + t];
            #pragma unroll
            for (int j = 0; j < 8; ++j) { ax += v[j].x; ay += v[j].y; az += v[j].z; aw += v[j].w; }
        }
        for (; i < cntok; ++i) {
            float4 v = bp[(size_t)i * 192 + t];
            ax += v.x; ay += v.y; az += v.z; aw += v.w;
        }
        const float inv = (cntok > 0) ? 1.0f / (float)cntok : 0.0f;
        unsigned p0 = pack_bf16x2(ax * inv, ay * inv);
        unsigned p1 = pack_bf16x2(az * inv, aw * inv);
        uint2 pk = {p0, p1};
        *(uint2*)(sentb + (size_t)sidx * HID + t * 4) = pk;   // one 8B store
    }
}

// ---------------------------------------------------------------------------
// K2: GEMM1  x1 = GELU(sentb[512,768] @ W1[768,4096] + b1), bf16 out.
// B staged directly from native fp32 [K][N]: each thread loads two k-rows x
// 16 n as float4s, packs bf16x2 along k, ds_write_b32 into Bl[n][k].
// 64x64 tile, BK=128, grid (8,64) m-fastest so the 8 blocks sharing a B
// column-slice are consecutive (same XCD L2). 4 waves 2x2, 16 MFMA/iter.
// Epilogue bounces through LDS for coalesced 32B stores.
// ---------------------------------------------------------------------------
__global__ __launch_bounds__(256) void gemm1_kernel(const __hip_bfloat16* __restrict__ A,
                                                    const float* __restrict__ W1,
                                                    const float* __restrict__ bias,
                                                    __hip_bfloat16* __restrict__ out) {
    const int m0 = blockIdx.x * 64;
    const int n0 = blockIdx.y * 64;
    const int t = threadIdx.x;
    const int w = t >> 6, l = t & 63;
    const int wm = (w >> 1) * 32;
    const int wn = (w & 1) * 32;

    __shared__ __hip_bfloat16 Al[64][136];
    __shared__ __hip_bfloat16 Bl[64][136];

    floatx4 acc[2][2] = {};

    const int r  = t >> 2;            // 0..63 (A row)
    const int ch = (t & 3) * 32;      // A k-chunk
    const __hip_bfloat16* Ag = A + (size_t)(m0 + r) * 768 + ch;

    const int kp   = t >> 2;          // 0..63 -> B k-pair 2*kp
    const int nseg = (t & 3) * 16;    // B n-segment

    const int lr = l & 15;
    const int kq = (l >> 4) * 8;

    for (int k0 = 0; k0 < 768; k0 += 128) {
        short8 av[4];
        #pragma unroll
        for (int q = 0; q < 4; ++q) av[q] = *(const short8*)(Ag + k0 + q * 8);

        const float* bp0 = W1 + (size_t)(k0 + 2 * kp) * 4096 + n0 + nseg;
        const float* bp1 = bp0 + 4096;
        float fa[16], fb[16];
        #pragma unroll
        for (int q = 0; q < 4; ++q) {
            float4 v0 = ((const float4*)bp0)[q];
            float4 v1 = ((const float4*)bp1)[q];
            fa[q*4+0] = v0.x; fa[q*4+1] = v0.y; fa[q*4+2] = v0.z; fa[q*4+3] = v0.w;
            fb[q*4+0] = v1.x; fb[q*4+1] = v1.y; fb[q*4+2] = v1.z; fb[q*4+3] = v1.w;
        }

        __syncthreads();                       // prior iter's frag reads done
        #pragma unroll
        for (int q = 0; q < 4; ++q) *(short8*)(&Al[r][ch + q * 8]) = av[q];
        #pragma unroll
        for (int j = 0; j < 16; ++j)
            *(unsigned*)(&Bl[nseg + j][2 * kp]) = pack_bf16x2(fa[j], fb[j]);
        __syncthreads();

        #pragma unroll
        for (int ks = 0; ks < 128; ks += 32) {
            short8 a0 = *(const short8*)(&Al[wm + lr][ks + kq]);
            short8 a1 = *(const short8*)(&Al[wm + 16 + lr][ks + kq]);
            short8 b0 = *(const short8*)(&Bl[wn + lr][ks + kq]);
            short8 b1 = *(const short8*)(&Bl[wn + 16 + lr][ks + kq]);
            acc[0][0] = __builtin_amdgcn_mfma_f32_16x16x32_bf16(a0, b0, acc[0][0], 0, 0, 0);
            acc[0][1] = __builtin_amdgcn_mfma_f32_16x16x32_bf16(a0, b1, acc[0][1], 0, 0, 0);
            acc[1][0] = __builtin_amdgcn_mfma_f32_16x16x32_bf16(a1, b0, acc[1][0], 0, 0, 0);
            acc[1][1] = __builtin_amdgcn_mfma_f32_16x16x32_bf16(a1, b1, acc[1][1], 0, 0, 0);
        }
    }

    // ---- epilogue: bias + GELU -> LDS [64][72] -> coalesced 32B stores ----
    __syncthreads();
    __hip_bfloat16* E = &Al[0][0];              // reuse, stride 72
    #pragma unroll
    for (int i = 0; i < 2; ++i) {
        #pragma unroll
        for (int j = 0; j < 2; ++j) {
            const int cl = wn + j * 16 + lr;
            const float bv = bias[n0 + cl];
            #pragma unroll
            for (int rg = 0; rg < 4; ++rg) {
                const int rl = wm + i * 16 + (l >> 4) * 4 + rg;
                float x = acc[i][j][rg] + bv;
                E[rl * 72 + cl] = __float2bfloat16(gelu_exact(x));
            }
        }
    }
    __syncthreads();
    {
        const int rr  = t >> 2;
        const int seg = (t & 3) * 16;
        short8 v0 = *(const short8*)(&E[rr * 72 + seg]);
        short8 v1 = *(const short8*)(&E[rr * 72 + seg + 8]);
        __hip_bfloat16* op = out + (size_t)(m0 + rr) * 4096 + n0 + seg;
        *(short8*)(op)     = v0;
        *(short8*)(op + 8) = v1;
    }
}

// ---------------------------------------------------------------------------
// K3: GEMM2 split-K=8 with atomic accumulation into x2 + fused head.
// B staged directly from native fp32 W2[4096,256]. Grid (8,4,8) m-fastest.
// Each block atomicAdds its 64x64 fp32 tile into x2; per-m-tile completion
// counter elects the 32nd block to run b2+GELU+head for its 64 rows.
// ---------------------------------------------------------------------------
__global__ __launch_bounds__(256) void gemm2_kernel(const __hip_bfloat16* __restrict__ A,
                                                    const float* __restrict__ W2,
                                                    const float* __restrict__ b2,
                                                    const float* __restrict__ W3,
                                                    const float* __restrict__ b3,
                                                    float* __restrict__ x2,
                                                    int* __restrict__ cnt,
                                                    float* __restrict__ out) {
    const int m0 = blockIdx.x * 64;
    const int n0 = blockIdx.y * 64;
    const int s  = blockIdx.z;
    const int kb = s * 512;
    const int t = threadIdx.x;
    const int w = t >> 6, l = t & 63;
    const int wm = (w >> 1) * 32;
    const int wn = (w & 1) * 32;

    __shared__ __hip_bfloat16 Al[64][136];
    __shared__ __hip_bfloat16 Bl[64][136];
    __shared__ int lastflag;

    floatx4 acc[2][2] = {};

    const int r  = t >> 2;
    const int ch = (t & 3) * 32;
    const __hip_bfloat16* Ag = A + (size_t)(m0 + r) * 4096 + kb + ch;

    const int kp   = t >> 2;
    const int nseg = (t & 3) * 16;

    const int lr = l & 15;
    const int kq = (l >> 4) * 8;

    for (int k0 = 0; k0 < 512; k0 += 128) {
        short8 av[4];
        #pragma unroll
        for (int q = 0; q < 4; ++q) av[q] = *(const short8*)(Ag + k0 + q * 8);

        const float* bp0 = W2 + (size_t)(kb + k0 + 2 * kp) * 256 + n0 + nseg;
        const float* bp1 = bp0 + 256;
        float fa[16], fb[16];
        #pragma unroll
        for (int q = 0; q < 4; ++q) {
            float4 v0 = ((const float4*)bp0)[q];
            float4 v1 = ((const float4*)bp1)[q];
            fa[q*4+0] = v0.x; fa[q*4+1] = v0.y; fa[q*4+2] = v0.z; fa[q*4+3] = v0.w;
            fb[q*4+0] = v1.x; fb[q*4+1] = v1.y; fb[q*4+2] = v1.z; fb[q*4+3] = v1.w;
        }

        __syncthreads();
        #pragma unroll
        for (int q = 0; q < 4; ++q) *(short8*)(&Al[r][ch + q * 8]) = av[q];
        #pragma unroll
        for (int j = 0; j < 16; ++j)
            *(unsigned*)(&Bl[nseg + j][2 * kp]) = pack_bf16x2(fa[j], fb[j]);
        __syncthreads();

        #pragma unroll
        for (int ks = 0; ks < 128; ks += 32) {
            short8 a0 = *(const short8*)(&Al[wm + lr][ks + kq]);
            short8 a1 = *(const short8*)(&Al[wm + 16 + lr][ks + kq]);
            short8 b0 = *(const short8*)(&Bl[wn + lr][ks + kq]);
            short8 b1 = *(const short8*)(&Bl[wn + 16 + lr][ks + kq]);
            acc[0][0] = __builtin_amdgcn_mfma_f32_16x16x32_bf16(a0, b0, acc[0][0], 0, 0, 0);
            acc[0][1] = __builtin_amdgcn_mfma_f32_16x16x32_bf16(a0, b1, acc[0][1], 0, 0, 0);
            acc[1][0] = __builtin_amdgcn_mfma_f32_16x16x32_bf16(a1, b0, acc[1][0], 0, 0, 0);
            acc[1][1] = __builtin_amdgcn_mfma_f32_16x16x32_bf16(a1, b1, acc[1][1], 0, 0, 0);
        }
    }

    // ---- accumulate into x2 ----
    #pragma unroll
    for (int i = 0; i < 2; ++i) {
        #pragma unroll
        for (int j = 0; j < 2; ++j) {
            const int col  = n0 + wn + j * 16 + lr;
            const int rowb = m0 + wm + i * 16 + (l >> 4) * 4;
            #pragma unroll
            for (int rg = 0; rg < 4; ++rg)
                atomicAdd(&x2[(size_t)(rowb + rg) * 256 + col], acc[i][j][rg]);
        }
    }

    // ---- completion counter: last of 32 blocks for this m-tile runs head ----
    __threadfence();                       // release our x2 adds
    __syncthreads();
    if (t == 0) {
        int old = atomicAdd(&cnt[blockIdx.x], 1);
        lastflag = (old == 31);
    }
    __syncthreads();
    if (!lastflag) return;
    __threadfence();                       // acquire others' x2 adds

    // head: wave w handles row m0 + it*4 + w; lane l covers cols l+64q.
    for (int it = 0; it < 16; ++it) {
        const int row = m0 + it * 4 + w;
        float y0 = 0.f, y1 = 0.f;
        #pragma unroll
        for (int q = 0; q < 4; ++q) {
            const int col = l + 64 * q;
            const float v = x2[(size_t)row * 256 + col];
            const float x = gelu_exact(v + b2[col]);
            y0 += x * W3[col * 2 + 0];
            y1 += x * W3[col * 2 + 1];
        }
        #pragma unroll
        for (int off = 32; off; off >>= 1) {
            y0 += __shfl_down(y0, off);
            y1 += __shfl_down(y1, off);
        }
        if (l == 0) {
            out[row * 2 + 0] = y0 + b3[0];
            out[row * 2 + 1] = y1 + b3[1];
        }
    }
}

// ---------------------------------------------------------------------------
extern "C" void kernel_launch(void* const* d_in, const int* in_sizes, int n_in,
                              void* d_out, int out_size, void* d_ws, size_t ws_size,
                              hipStream_t stream) {
    const float* hidden = (const float*)d_in[0];
    const int*   ids    = (const int*)d_in[1];
    const float* W1     = (const float*)d_in[2];
    const float* b1     = (const float*)d_in[3];
    const float* W2     = (const float*)d_in[4];
    const float* b2     = (const float*)d_in[5];
    const float* W3     = (const float*)d_in[6];
    const float* b3     = (const float*)d_in[7];
    float* out = (float*)d_out;

    char* ws = (char*)d_ws;
    __hip_bfloat16* sentb = (__hip_bfloat16*)(ws + 0);         // 512x768 bf16
    __hip_bfloat16* x1    = (__hip_bfloat16*)(ws + 786432);    // 512x4096 bf16
    float* x2             = (float*)(ws + 4980736);            // 512x256 f32
    int*   cnt            = (int*)(ws + 5505024);              // 16 ints
    // total ws use: ~5.5 MB

    stage1_kernel<<<528, 256, 0, stream>>>(ids, hidden, sentb, x2, cnt);
    gemm1_kernel<<<dim3(8, 64), 256, 0, stream>>>(sentb, W1, b1, x1);
    gemm2_kernel<<<dim3(8, 4, 8), 256, 0, stream>>>(x1, W2, b2, W3, b3, x2, cnt, out);
}